// Round 2
// baseline (324.006 us; speedup 1.0000x reference)
//
#include <hip/hip_runtime.h>

// Problem constants (B=2, C=64, C8=8, H=W=96 -> N=9216)
#define NTOK  9216
#define NBAT  2

typedef __attribute__((ext_vector_type(8))) short bf16x8;
typedef __attribute__((ext_vector_type(4))) float f32x4;

__device__ __forceinline__ unsigned short f2bf(float x) {
  unsigned int u = __builtin_bit_cast(unsigned int, x);
  u += 0x7fffu + ((u >> 16) & 1u);   // RNE
  return (unsigned short)(u >> 16);
}

// ---------------------------------------------------------------------------
// Kernel 1: QKV projections -> bf16.
//   qg[b][n][8], kg[b][n][8] (16 B rows = one K=32 mfma frag, quads>=1 zeroed)
//   vg[b][c][n]  (c-major rows so V A-frags are contiguous in j)
// Re-sliced for occupancy: grid = B * 144 n-tiles * 10 row-groups = 2880
// blocks; each thread computes 2 adjacent output rows for one n. x reads are
// coalesced global (no LDS, no barrier); W rows are wave-uniform -> s_load.
// ---------------------------------------------------------------------------
__global__ __launch_bounds__(256) void qkv_proj(
    const float* __restrict__ x,
    const float* __restrict__ Wq, const float* __restrict__ bq,
    const float* __restrict__ Wk, const float* __restrict__ bk,
    const float* __restrict__ Wv, const float* __restrict__ bv,
    unsigned short* __restrict__ qg, unsigned short* __restrict__ kg,
    unsigned short* __restrict__ vg)
{
  const int bid = blockIdx.x;
  const int rg  = bid % 10;          // row-group: 8 rows of the 80
  const int t2  = bid / 10;
  const int nt  = t2 % 144;
  const int b   = t2 / 144;
  const int t   = threadIdx.x;
  const int n   = nt * 64 + (t & 63);
  const int g   = t >> 6;            // wave id 0..3 (wave-uniform)
  const int r0  = rg * 8 + g * 2;    // first of this thread's 2 rows (0..79)

  const float *wr0, *wr1;
  float bz0, bz1;
  if (r0 < 8)       { wr0 = Wq + r0 * 64;        bz0 = bq[r0];      bz1 = bq[r0 + 1]; }
  else if (r0 < 16) { wr0 = Wk + (r0 - 8) * 64;  bz0 = bk[r0 - 8];  bz1 = bk[r0 - 7]; }
  else              { wr0 = Wv + (r0 - 16) * 64; bz0 = bv[r0 - 16]; bz1 = bv[r0 - 15]; }
  wr1 = wr0 + 64;

  const float* xc = x + (size_t)b * 64 * NTOK + n;
  float a0 = 0.f, a1 = 0.f;
  #pragma unroll
  for (int c = 0; c < 64; c++) {
    float xv = xc[(size_t)c * NTOK];
    a0 = fmaf(wr0[c], xv, a0);
    a1 = fmaf(wr1[c], xv, a1);
  }
  unsigned short o0 = f2bf(a0 + bz0), o1 = f2bf(a1 + bz1);

  if (r0 < 8) {
    qg[((size_t)b * NTOK + n) * 8 + r0]     = o0;
    qg[((size_t)b * NTOK + n) * 8 + r0 + 1] = o1;
  } else if (r0 < 16) {
    kg[((size_t)b * NTOK + n) * 8 + r0 - 8] = o0;
    kg[((size_t)b * NTOK + n) * 8 + r0 - 7] = o1;
  } else {
    vg[(size_t)(b * 64 + r0 - 16) * NTOK + n] = o0;
    vg[(size_t)(b * 64 + r0 - 15) * NTOK + n] = o1;
  }
}

// ---------------------------------------------------------------------------
// Kernel 2: fused flash attention + epilogue, in-block split-j.
// Block: 256 thr = 4 waves; block owns 16 query rows; wave w processes
// j-chunks {w*64 + it*256}. No __syncthreads in the main loop: V/K frags come
// straight from global (L1/L2-resident), P round-trips through a PER-WAVE LDS
// tile (same-wave ordering via lgkmcnt). End-of-kernel: merge the 4 waves'
// (m, l, O-partial) through LDS, normalize, add residual.
// ---------------------------------------------------------------------------
__global__ __launch_bounds__(256) void flash_attn(
    const float* __restrict__ x,
    const unsigned short* __restrict__ qg,
    const unsigned short* __restrict__ kg,
    const unsigned short* __restrict__ vg,
    const float* __restrict__ gamma_p,
    const float* __restrict__ dyn_p,
    float* __restrict__ y)
{
  __shared__ __align__(16) unsigned short p_lds[4 * 16 * 72]; // per-wave [i][j]
  __shared__ float ml[4][2][16];      // [wave][m/l][i]
  __shared__ float obuf[4][64][17];   // [wave][c][i] (+1 pad)
  __shared__ float Ltot_s[16];

  const int bid  = blockIdx.x;
  const int b    = bid / 576;
  const int rt   = bid % 576;
  const int tid  = threadIdx.x;
  const int w    = tid >> 6;
  const int lane = tid & 63;
  const int i16  = lane & 15;
  const int quad = lane >> 4;
  const int i0   = rt * 16;          // this block's 16 query rows

  unsigned short* pw = &p_lds[w * 16 * 72];

  // Q B-frag (K=32, real k<8 -> only quad 0 nonzero)
  bf16x8 qf = {};
  if (quad == 0)
    qf = *(const bf16x8*)(qg + ((size_t)b * NTOK + i0 + i16) * 8);

  f32x4 acc[4];
  #pragma unroll
  for (int ct = 0; ct < 4; ct++) acc[ct] = (f32x4){0.f, 0.f, 0.f, 0.f};
  float m = -3.0e38f, l = 0.f;
  const f32x4 z4 = {0.f, 0.f, 0.f, 0.f};

  const size_t vbase = (size_t)b * 64 * NTOK;
  const size_t kbase = (size_t)b * NTOK * 8;

  for (int it = 0; it < 36; ++it) {
    const int j0 = (w << 6) + (it << 8);   // this wave's 64-key chunk

    // ---- S^T tiles: st[jt] holds e[i = i16][j = j0 + jt*16 + quad*4 + r]
    f32x4 st[4];
    #pragma unroll
    for (int jt = 0; jt < 4; jt++) {
      bf16x8 kf = {};
      if (quad == 0)
        kf = *(const bf16x8*)(kg + kbase + (size_t)(j0 + jt * 16 + i16) * 8);
      st[jt] = __builtin_amdgcn_mfma_f32_16x16x32_bf16(kf, qf, z4, 0, 0, 0);
    }

    // ---- online softmax for row i16 (this lane holds 16 of the 64 chunk e's)
    float emax = st[0][0];
    #pragma unroll
    for (int jt = 0; jt < 4; jt++)
      #pragma unroll
      for (int r = 0; r < 4; r++) emax = fmaxf(emax, st[jt][r]);
    emax = fmaxf(emax, __shfl_xor(emax, 16));
    emax = fmaxf(emax, __shfl_xor(emax, 32));
    float mn    = fmaxf(m, emax);
    float alpha = __expf(m - mn);
    float ps = 0.f;
    #pragma unroll
    for (int jt = 0; jt < 4; jt++) {
      float p0 = __expf(st[jt][0] - mn);
      float p1 = __expf(st[jt][1] - mn);
      float p2 = __expf(st[jt][2] - mn);
      float p3 = __expf(st[jt][3] - mn);
      ps += (p0 + p1) + (p2 + p3);
      unsigned int lo = (unsigned int)f2bf(p0) | ((unsigned int)f2bf(p1) << 16);
      unsigned int hi = (unsigned int)f2bf(p2) | ((unsigned int)f2bf(p3) << 16);
      *(uint2*)(&pw[i16 * 72 + jt * 16 + quad * 4]) = make_uint2(lo, hi);
    }
    ps += __shfl_xor(ps, 16);
    ps += __shfl_xor(ps, 32);
    l = l * alpha + ps;
    m = mn;
    #pragma unroll
    for (int ct = 0; ct < 4; ct++)
      #pragma unroll
      for (int r = 0; r < 4; r++) acc[ct][r] *= alpha;

    // ---- O^T += V · P^T  (per-wave P tile; no cross-wave sync needed)
    bf16x8 pf0 = *(const bf16x8*)(&pw[i16 * 72 + quad * 8]);
    bf16x8 pf1 = *(const bf16x8*)(&pw[i16 * 72 + 32 + quad * 8]);
    #pragma unroll
    for (int ct = 0; ct < 4; ct++) {
      const unsigned short* vp = vg + vbase + (size_t)(ct * 16 + i16) * NTOK + j0;
      bf16x8 vf0 = *(const bf16x8*)(vp + quad * 8);
      bf16x8 vf1 = *(const bf16x8*)(vp + 32 + quad * 8);
      acc[ct] = __builtin_amdgcn_mfma_f32_16x16x32_bf16(vf0, pf0, acc[ct], 0, 0, 0);
      acc[ct] = __builtin_amdgcn_mfma_f32_16x16x32_bf16(vf1, pf1, acc[ct], 0, 0, 0);
    }
  }

  // ---- merge the 4 waves' partials (each wave covered a j-subset)
  if (quad == 0) { ml[w][0][i16] = m; ml[w][1][i16] = l; }
  __syncthreads();

  const float M = fmaxf(fmaxf(ml[0][0][i16], ml[1][0][i16]),
                        fmaxf(ml[2][0][i16], ml[3][0][i16]));
  const float beta = __expf(m - M);
  #pragma unroll
  for (int ct = 0; ct < 4; ct++)
    #pragma unroll
    for (int r = 0; r < 4; r++)
      obuf[w][ct * 16 + quad * 4 + r][i16] = acc[ct][r] * beta;
  if (w == 0 && quad == 0) {
    float L = ml[0][1][i16] * __expf(ml[0][0][i16] - M)
            + ml[1][1][i16] * __expf(ml[1][0][i16] - M)
            + ml[2][1][i16] * __expf(ml[2][0][i16] - M)
            + ml[3][1][i16] * __expf(ml[3][0][i16] - M);
    Ltot_s[i16] = L;
  }
  __syncthreads();

  // ---- epilogue: y = gamma*dyn/L * O + x   (1024 outputs, 4 per thread)
  const float gs = gamma_p[0] * dyn_p[0];
  #pragma unroll
  for (int e0 = 0; e0 < 4; e0++) {
    int e = tid + e0 * 256;
    int c = e >> 4, i = e & 15;
    float o = obuf[0][c][i] + obuf[1][c][i] + obuf[2][c][i] + obuf[3][c][i];
    size_t a = (size_t)(b * 64 + c) * NTOK + i0 + i;
    y[a] = o * gs / Ltot_s[i] + x[a];
  }
}

// ---------------------------------------------------------------------------
extern "C" void kernel_launch(void* const* d_in, const int* in_sizes, int n_in,
                              void* d_out, int out_size, void* d_ws, size_t ws_size,
                              hipStream_t stream) {
  const float* x     = (const float*)d_in[0];
  const float* Wq    = (const float*)d_in[1];
  const float* bq    = (const float*)d_in[2];
  const float* Wk    = (const float*)d_in[3];
  const float* bk    = (const float*)d_in[4];
  const float* Wv    = (const float*)d_in[5];
  const float* bv    = (const float*)d_in[6];
  const float* gamma = (const float*)d_in[7];
  const float* dyn   = (const float*)d_in[8];
  float* y = (float*)d_out;

  // workspace: qg | kg | vg  (bf16)
  unsigned short* qg = (unsigned short*)d_ws;              // B*N*8
  unsigned short* kg = qg + (size_t)NBAT * NTOK * 8;       // B*N*8
  unsigned short* vg = kg + (size_t)NBAT * NTOK * 8;       // B*64*N

  qkv_proj<<<NBAT * 144 * 10, 256, 0, stream>>>(x, Wq, bq, Wk, bk, Wv, bv, qg, kg, vg);
  flash_attn<<<NBAT * 576, 256, 0, stream>>>(x, qg, kg, vg, gamma, dyn, y);
}

// Round 3
// 258.351 us; speedup vs baseline: 1.2541x; 1.2541x over previous
//
#include <hip/hip_runtime.h>

// Problem constants (B=2, C=64, C8=8, H=W=96 -> N=9216)
#define NTOK  9216
#define NBAT  2

typedef __attribute__((ext_vector_type(8))) short bf16x8;
typedef __attribute__((ext_vector_type(4))) float f32x4;

#if __has_builtin(__builtin_amdgcn_exp2f)
#define EXP2(x) __builtin_amdgcn_exp2f(x)
#else
#define EXP2(x) exp2f(x)
#endif
#define L2E 1.4426950408889634f

__device__ __forceinline__ unsigned short f2bf(float x) {
  unsigned int u = __builtin_bit_cast(unsigned int, x);
  u += 0x7fffu + ((u >> 16) & 1u);   // RNE
  return (unsigned short)(u >> 16);
}

// pack two non-negative floats to bf16x2 (round-half-up via +0x8000, v_perm)
__device__ __forceinline__ unsigned int pack_bf2(float lo, float hi) {
  unsigned int ulo = __builtin_bit_cast(unsigned int, lo) + 0x8000u;
  unsigned int uhi = __builtin_bit_cast(unsigned int, hi) + 0x8000u;
  return __builtin_amdgcn_perm(uhi, ulo, 0x07060302u);
}

// ---------------------------------------------------------------------------
// Kernel 1: QKV projections -> bf16.
//   qg[b][n][8], kg[b][n][8] (16 B rows = one K=32 mfma frag, quads>=1 zeroed)
//   vg[b][c][n]  (c-major rows so V A-frags are contiguous in j)
// Grid = B * 144 n-tiles * 5 row-groups(16) = 1440 blocks, 256 thr.
// x tile staged in LDS once; each WAVE owns 4 consecutive output rows
// (wave-uniform -> W via scalar loads); each thread: 4 rows x 1 n.
// ---------------------------------------------------------------------------
__global__ __launch_bounds__(256) void qkv_proj(
    const float* __restrict__ x,
    const float* __restrict__ Wq, const float* __restrict__ bq,
    const float* __restrict__ Wk, const float* __restrict__ bk,
    const float* __restrict__ Wv, const float* __restrict__ bv,
    unsigned short* __restrict__ qg, unsigned short* __restrict__ kg,
    unsigned short* __restrict__ vg)
{
  __shared__ __align__(16) float xl[64 * 68];
  const int bid = blockIdx.x;
  const int rg  = bid % 5;
  const int t2  = bid / 5;
  const int nt  = t2 % 144;
  const int b   = t2 / 144;
  const int t   = threadIdx.x;
  const int lane = t & 63;
  const int n0  = nt * 64;

  #pragma unroll
  for (int kk = 0; kk < 4; kk++) {
    int p = t + kk * 256;
    int c = p >> 4, n4 = (p & 15) << 2;
    *(float4*)(&xl[c * 68 + n4]) =
        *(const float4*)(x + (size_t)(b * 64 + c) * NTOK + n0 + n4);
  }
  __syncthreads();

  const int g  = __builtin_amdgcn_readfirstlane(t >> 6);  // wave id 0..3
  const int r0 = rg * 16 + g * 4;                         // rows r0..r0+3 (0..79)

  const float* wbase; const float* bias_p; int lr0;
  if (r0 < 8)       { wbase = Wq; bias_p = bq; lr0 = r0; }
  else if (r0 < 16) { wbase = Wk; bias_p = bk; lr0 = r0 - 8; }
  else              { wbase = Wv; bias_p = bv; lr0 = r0 - 16; }
  const float* w0 = wbase + lr0 * 64;

  float a0 = 0.f, a1 = 0.f, a2 = 0.f, a3 = 0.f;
  #pragma unroll 16
  for (int c = 0; c < 64; c++) {
    float xv = xl[c * 68 + lane];
    a0 = fmaf(w0[c],       xv, a0);
    a1 = fmaf(w0[64 + c],  xv, a1);
    a2 = fmaf(w0[128 + c], xv, a2);
    a3 = fmaf(w0[192 + c], xv, a3);
  }
  a0 += bias_p[lr0]; a1 += bias_p[lr0 + 1];
  a2 += bias_p[lr0 + 2]; a3 += bias_p[lr0 + 3];

  const int n = n0 + lane;
  if (r0 < 16) {
    ushort4 o;
    o.x = f2bf(a0); o.y = f2bf(a1); o.z = f2bf(a2); o.w = f2bf(a3);
    unsigned short* dst = (r0 < 8) ? qg : kg;
    *(ushort4*)(dst + ((size_t)b * NTOK + n) * 8 + lr0) = o;
  } else {
    vg[(size_t)(b * 64 + lr0)     * NTOK + n] = f2bf(a0);
    vg[(size_t)(b * 64 + lr0 + 1) * NTOK + n] = f2bf(a1);
    vg[(size_t)(b * 64 + lr0 + 2) * NTOK + n] = f2bf(a2);
    vg[(size_t)(b * 64 + lr0 + 3) * NTOK + n] = f2bf(a3);
  }
}

// ---------------------------------------------------------------------------
// Kernel 2: fused flash attention + epilogue, in-block split-j.
// Block: 256 thr = 4 waves; block owns 16 query rows; wave w handles j-chunks
// {w*64 + it*256}. Per-iteration pipeline: V frags issued at top (consumed
// after softmax), K frags double-buffered (loaded one iter ahead) -> S^T mfma
// never waits on VMEM. Softmax in log2 domain; per-lane l partial (alpha is
// row-uniform), reduced once at the end. P round-trips through per-wave LDS.
// ---------------------------------------------------------------------------
__global__ __launch_bounds__(256) void flash_attn(
    const float* __restrict__ x,
    const unsigned short* __restrict__ qg,
    const unsigned short* __restrict__ kg,
    const unsigned short* __restrict__ vg,
    const float* __restrict__ gamma_p,
    const float* __restrict__ dyn_p,
    float* __restrict__ y)
{
  __shared__ __align__(16) unsigned short p_lds[4 * 16 * 72]; // per-wave [i][j]
  __shared__ float ml[4][2][16];      // [wave][m/l][i]  (m stored as m*log2e)
  __shared__ float obuf[4][64][17];   // [wave][c][i] (+1 pad)
  __shared__ float Ltot_s[16];

  const int bid  = blockIdx.x;
  const int b    = bid / 576;
  const int rt   = bid % 576;
  const int tid  = threadIdx.x;
  const int w    = tid >> 6;
  const int lane = tid & 63;
  const int i16  = lane & 15;
  const int quad = lane >> 4;
  const int i0   = rt * 16;          // this block's 16 query rows

  unsigned short* pw = &p_lds[w * 16 * 72];

  // Q B-frag (K=32, real k<8 -> only quad 0 nonzero; this zeroing makes the
  // A-operand (K frag) garbage on quads 1-3 irrelevant: it multiplies 0)
  bf16x8 qf = {};
  if (quad == 0)
    qf = *(const bf16x8*)(qg + ((size_t)b * NTOK + i0 + i16) * 8);

  f32x4 acc[4];
  #pragma unroll
  for (int ct = 0; ct < 4; ct++) acc[ct] = (f32x4){0.f, 0.f, 0.f, 0.f};
  float mlg = -3.0e38f;   // running row max, log2 domain (m * log2e)
  float lp  = 0.f;        // per-lane partial of l (this lane's 16 j's)
  const f32x4 z4 = {0.f, 0.f, 0.f, 0.f};

  const size_t vbase = (size_t)b * 64 * NTOK;
  const size_t kbase = (size_t)b * NTOK * 8;

  // K frags for it=0 (unconditional: rows broadcast across quads)
  bf16x8 kfc[4];
  {
    const unsigned short* kp = kg + kbase + (size_t)((w << 6) + i16) * 8;
    #pragma unroll
    for (int jt = 0; jt < 4; jt++) kfc[jt] = *(const bf16x8*)(kp + jt * 128);
  }

  for (int it = 0; it < 36; ++it) {
    const int j0 = (w << 6) + (it << 8);   // this wave's 64-key chunk

    // ---- V frags for THIS iteration: issue now, consume after softmax
    bf16x8 vf[8];
    #pragma unroll
    for (int ct = 0; ct < 4; ct++) {
      const unsigned short* vp = vg + vbase + (size_t)(ct * 16 + i16) * NTOK + j0;
      vf[2 * ct]     = *(const bf16x8*)(vp + quad * 8);
      vf[2 * ct + 1] = *(const bf16x8*)(vp + 32 + quad * 8);
    }
    // ---- K frags for NEXT iteration (wrap harmlessly on last iter)
    bf16x8 kfn[4];
    {
      const int j1 = (it == 35) ? (w << 6) : j0 + 256;
      const unsigned short* kp = kg + kbase + (size_t)(j1 + i16) * 8;
      #pragma unroll
      for (int jt = 0; jt < 4; jt++) kfn[jt] = *(const bf16x8*)(kp + jt * 128);
    }

    // ---- S^T tiles: st[jt] holds e[i = i16][j = j0 + jt*16 + quad*4 + r]
    f32x4 st[4];
    #pragma unroll
    for (int jt = 0; jt < 4; jt++)
      st[jt] = __builtin_amdgcn_mfma_f32_16x16x32_bf16(kfc[jt], qf, z4, 0, 0, 0);

    // ---- online softmax (log2 domain) for row i16
    float emax = st[0][0];
    #pragma unroll
    for (int jt = 0; jt < 4; jt++)
      #pragma unroll
      for (int r = 0; r < 4; r++) emax = fmaxf(emax, st[jt][r]);
    emax = fmaxf(emax, __shfl_xor(emax, 16));
    emax = fmaxf(emax, __shfl_xor(emax, 32));
    const float mnl   = fmaxf(mlg, emax * L2E);
    const float alpha = EXP2(mlg - mnl);
    float ps = 0.f;
    #pragma unroll
    for (int jt = 0; jt < 4; jt++) {
      float p0 = EXP2(fmaf(st[jt][0], L2E, -mnl));
      float p1 = EXP2(fmaf(st[jt][1], L2E, -mnl));
      float p2 = EXP2(fmaf(st[jt][2], L2E, -mnl));
      float p3 = EXP2(fmaf(st[jt][3], L2E, -mnl));
      ps += (p0 + p1) + (p2 + p3);
      unsigned int lo = pack_bf2(p0, p1);
      unsigned int hi = pack_bf2(p2, p3);
      *(uint2*)(&pw[i16 * 72 + jt * 16 + quad * 4]) = make_uint2(lo, hi);
    }
    lp  = lp * alpha + ps;
    mlg = mnl;
    #pragma unroll
    for (int ct = 0; ct < 4; ct++)
      #pragma unroll
      for (int r = 0; r < 4; r++) acc[ct][r] *= alpha;

    // ---- O^T += V · P^T  (per-wave P tile; same-wave lgkmcnt ordering)
    bf16x8 pf0 = *(const bf16x8*)(&pw[i16 * 72 + quad * 8]);
    bf16x8 pf1 = *(const bf16x8*)(&pw[i16 * 72 + 32 + quad * 8]);
    #pragma unroll
    for (int ct = 0; ct < 4; ct++) {
      acc[ct] = __builtin_amdgcn_mfma_f32_16x16x32_bf16(vf[2 * ct],     pf0, acc[ct], 0, 0, 0);
      acc[ct] = __builtin_amdgcn_mfma_f32_16x16x32_bf16(vf[2 * ct + 1], pf1, acc[ct], 0, 0, 0);
    }
    #pragma unroll
    for (int jt = 0; jt < 4; jt++) kfc[jt] = kfn[jt];
  }

  // ---- reduce per-lane l over the 4 quads of this row
  lp += __shfl_xor(lp, 16);
  lp += __shfl_xor(lp, 32);

  // ---- merge the 4 waves' partials (each wave covered a j-subset)
  if (quad == 0) { ml[w][0][i16] = mlg; ml[w][1][i16] = lp; }
  __syncthreads();

  const float M = fmaxf(fmaxf(ml[0][0][i16], ml[1][0][i16]),
                        fmaxf(ml[2][0][i16], ml[3][0][i16]));
  const float beta = EXP2(mlg - M);
  #pragma unroll
  for (int ct = 0; ct < 4; ct++)
    #pragma unroll
    for (int r = 0; r < 4; r++)
      obuf[w][ct * 16 + quad * 4 + r][i16] = acc[ct][r] * beta;
  if (w == 0 && quad == 0) {
    float L = ml[0][1][i16] * EXP2(ml[0][0][i16] - M)
            + ml[1][1][i16] * EXP2(ml[1][0][i16] - M)
            + ml[2][1][i16] * EXP2(ml[2][0][i16] - M)
            + ml[3][1][i16] * EXP2(ml[3][0][i16] - M);
    Ltot_s[i16] = L;
  }
  __syncthreads();

  // ---- epilogue: y = gamma*dyn/L * O + x   (1024 outputs, 4 per thread)
  const float gs = gamma_p[0] * dyn_p[0];
  #pragma unroll
  for (int e0 = 0; e0 < 4; e0++) {
    int e = tid + e0 * 256;
    int c = e >> 4, i = e & 15;
    float o = obuf[0][c][i] + obuf[1][c][i] + obuf[2][c][i] + obuf[3][c][i];
    size_t a = (size_t)(b * 64 + c) * NTOK + i0 + i;
    y[a] = o * gs / Ltot_s[i] + x[a];
  }
}

// ---------------------------------------------------------------------------
extern "C" void kernel_launch(void* const* d_in, const int* in_sizes, int n_in,
                              void* d_out, int out_size, void* d_ws, size_t ws_size,
                              hipStream_t stream) {
  const float* x     = (const float*)d_in[0];
  const float* Wq    = (const float*)d_in[1];
  const float* bq    = (const float*)d_in[2];
  const float* Wk    = (const float*)d_in[3];
  const float* bk    = (const float*)d_in[4];
  const float* Wv    = (const float*)d_in[5];
  const float* bv    = (const float*)d_in[6];
  const float* gamma = (const float*)d_in[7];
  const float* dyn   = (const float*)d_in[8];
  float* y = (float*)d_out;

  // workspace: qg | kg | vg  (bf16)
  unsigned short* qg = (unsigned short*)d_ws;              // B*N*8
  unsigned short* kg = qg + (size_t)NBAT * NTOK * 8;       // B*N*8
  unsigned short* vg = kg + (size_t)NBAT * NTOK * 8;       // B*64*N

  qkv_proj<<<NBAT * 144 * 5, 256, 0, stream>>>(x, Wq, bq, Wk, bk, Wv, bv, qg, kg, vg);
  flash_attn<<<NBAT * 576, 256, 0, stream>>>(x, qg, kg, vg, gamma, dyn, y);
}

// Round 4
// 248.141 us; speedup vs baseline: 1.3057x; 1.0411x over previous
//
#include <hip/hip_runtime.h>

// Problem constants (B=2, C=64, C8=8, H=W=96 -> N=9216)
#define NTOK  9216
#define NBAT  2

typedef __attribute__((ext_vector_type(8))) short bf16x8;
typedef __attribute__((ext_vector_type(4))) float f32x4;

#if __has_builtin(__builtin_amdgcn_exp2f)
#define EXP2(x) __builtin_amdgcn_exp2f(x)
#else
#define EXP2(x) exp2f(x)
#endif
#define L2E 1.4426950408889634f

__device__ __forceinline__ unsigned short f2bf(float x) {
  unsigned int u = __builtin_bit_cast(unsigned int, x);
  u += 0x7fffu + ((u >> 16) & 1u);   // RNE
  return (unsigned short)(u >> 16);
}

// pack two non-negative floats to bf16x2 (round-half-up via +0x8000, v_perm)
__device__ __forceinline__ unsigned int pack_bf2(float lo, float hi) {
  unsigned int ulo = __builtin_bit_cast(unsigned int, lo) + 0x8000u;
  unsigned int uhi = __builtin_bit_cast(unsigned int, hi) + 0x8000u;
  return __builtin_amdgcn_perm(uhi, ulo, 0x07060302u);
}

// ---------------------------------------------------------------------------
// Kernel 1: QKV projections -> bf16.
//   qg[b][n][8]  = (q + bq) * log2(e)   (softmax exp folded into Q scale)
//   kg[b][n][8], vg[b][c][n]
// ---------------------------------------------------------------------------
__global__ __launch_bounds__(256) void qkv_proj(
    const float* __restrict__ x,
    const float* __restrict__ Wq, const float* __restrict__ bq,
    const float* __restrict__ Wk, const float* __restrict__ bk,
    const float* __restrict__ Wv, const float* __restrict__ bv,
    unsigned short* __restrict__ qg, unsigned short* __restrict__ kg,
    unsigned short* __restrict__ vg)
{
  __shared__ __align__(16) float xl[64 * 68];
  const int bid = blockIdx.x;
  const int rg  = bid % 5;
  const int t2  = bid / 5;
  const int nt  = t2 % 144;
  const int b   = t2 / 144;
  const int t   = threadIdx.x;
  const int lane = t & 63;
  const int n0  = nt * 64;

  #pragma unroll
  for (int kk = 0; kk < 4; kk++) {
    int p = t + kk * 256;
    int c = p >> 4, n4 = (p & 15) << 2;
    *(float4*)(&xl[c * 68 + n4]) =
        *(const float4*)(x + (size_t)(b * 64 + c) * NTOK + n0 + n4);
  }
  __syncthreads();

  const int g  = __builtin_amdgcn_readfirstlane(t >> 6);  // wave id 0..3
  const int r0 = rg * 16 + g * 4;                         // rows r0..r0+3 (0..79)

  const float* wbase; const float* bias_p; int lr0;
  if (r0 < 8)       { wbase = Wq; bias_p = bq; lr0 = r0; }
  else if (r0 < 16) { wbase = Wk; bias_p = bk; lr0 = r0 - 8; }
  else              { wbase = Wv; bias_p = bv; lr0 = r0 - 16; }
  const float* w0 = wbase + lr0 * 64;

  float a0 = 0.f, a1 = 0.f, a2 = 0.f, a3 = 0.f;
  #pragma unroll 16
  for (int c = 0; c < 64; c++) {
    float xv = xl[c * 68 + lane];
    a0 = fmaf(w0[c],       xv, a0);
    a1 = fmaf(w0[64 + c],  xv, a1);
    a2 = fmaf(w0[128 + c], xv, a2);
    a3 = fmaf(w0[192 + c], xv, a3);
  }
  a0 += bias_p[lr0]; a1 += bias_p[lr0 + 1];
  a2 += bias_p[lr0 + 2]; a3 += bias_p[lr0 + 3];
  if (r0 < 8) { a0 *= L2E; a1 *= L2E; a2 *= L2E; a3 *= L2E; }  // wave-uniform

  const int n = n0 + lane;
  if (r0 < 16) {
    ushort4 o;
    o.x = f2bf(a0); o.y = f2bf(a1); o.z = f2bf(a2); o.w = f2bf(a3);
    unsigned short* dst = (r0 < 8) ? qg : kg;
    *(ushort4*)(dst + ((size_t)b * NTOK + n) * 8 + lr0) = o;
  } else {
    vg[(size_t)(b * 64 + lr0)     * NTOK + n] = f2bf(a0);
    vg[(size_t)(b * 64 + lr0 + 1) * NTOK + n] = f2bf(a1);
    vg[(size_t)(b * 64 + lr0 + 2) * NTOK + n] = f2bf(a2);
    vg[(size_t)(b * 64 + lr0 + 3) * NTOK + n] = f2bf(a3);
  }
}

// ---------------------------------------------------------------------------
// Kernel 2: flash partial, NO online max (energies bounded; softmax is
// shift-invariant; exp2 fp32 safe to |e|~80). Grid = B * 576 i-tiles * 2
// j-halves = 2304 blocks x 4 waves. Wave w covers chunks
// j = jh*4608 + w*64 + it*256, it<18. Loop has NO barriers, NO cross-lane
// ops, accumulate-only loop-carried deps, double-buffered per-wave P tile
// -> iterations can pipeline. Emits per-block O-partial (64x16 f32) and
// l-partial (16 f32) to workspace.
// ---------------------------------------------------------------------------
__global__ __launch_bounds__(256) void flash_partial(
    const unsigned short* __restrict__ qg,
    const unsigned short* __restrict__ kg,
    const unsigned short* __restrict__ vg,
    float* __restrict__ opart, float* __restrict__ lpart)
{
  __shared__ __align__(16) unsigned short p_lds[4 * 2 * 16 * 72]; // dbuf/wave
  __shared__ float l_s[4][16];

  const int bid  = blockIdx.x;
  const int jh   = bid & 1;
  const int rt   = (bid >> 1) % 576;
  const int b    = (bid >> 1) / 576;
  const int tid  = threadIdx.x;
  const int w    = tid >> 6;
  const int lane = tid & 63;
  const int i16  = lane & 15;
  const int quad = lane >> 4;
  const int i0   = rt * 16;
  const int jbase = jh * 4608 + (w << 6);

  unsigned short* pb = &p_lds[w * 2304];

  bf16x8 qf = {};
  if (quad == 0)
    qf = *(const bf16x8*)(qg + ((size_t)b * NTOK + i0 + i16) * 8);

  f32x4 acc[4];
  #pragma unroll
  for (int ct = 0; ct < 4; ct++) acc[ct] = (f32x4){0.f, 0.f, 0.f, 0.f};
  float lp = 0.f;
  const f32x4 z4 = {0.f, 0.f, 0.f, 0.f};

  const size_t vbase = (size_t)b * 64 * NTOK;
  const size_t kbase = (size_t)b * NTOK * 8;

  bf16x8 kfc[4];
  {
    const unsigned short* kp = kg + kbase + (size_t)(jbase + i16) * 8;
    #pragma unroll
    for (int jt = 0; jt < 4; jt++) kfc[jt] = *(const bf16x8*)(kp + jt * 128);
  }

  for (int it = 0; it < 18; ++it) {
    const int j0 = jbase + (it << 8);

    // V frags for THIS iteration (consumed after exp/pack -> latency hidden)
    bf16x8 vf[8];
    #pragma unroll
    for (int ct = 0; ct < 4; ct++) {
      const unsigned short* vp = vg + vbase + (size_t)(ct * 16 + i16) * NTOK + j0;
      vf[2 * ct]     = *(const bf16x8*)(vp + quad * 8);
      vf[2 * ct + 1] = *(const bf16x8*)(vp + 32 + quad * 8);
    }
    // K frags for NEXT iteration (wrap harmlessly on last)
    bf16x8 kfn[4];
    {
      const int j1 = (it == 17) ? jbase : j0 + 256;
      const unsigned short* kp = kg + kbase + (size_t)(j1 + i16) * 8;
      #pragma unroll
      for (int jt = 0; jt < 4; jt++) kfn[jt] = *(const bf16x8*)(kp + jt * 128);
    }

    // S^T: st[jt] = log2e * e[i=i16][j = j0 + jt*16 + quad*4 + r]
    f32x4 st[4];
    #pragma unroll
    for (int jt = 0; jt < 4; jt++)
      st[jt] = __builtin_amdgcn_mfma_f32_16x16x32_bf16(kfc[jt], qf, z4, 0, 0, 0);

    // p = exp2(st) directly (no shift, no max, no rescale)
    unsigned short* pw = pb + (it & 1) * 1152;
    float ps = 0.f;
    #pragma unroll
    for (int jt = 0; jt < 4; jt++) {
      float p0 = EXP2(st[jt][0]);
      float p1 = EXP2(st[jt][1]);
      float p2 = EXP2(st[jt][2]);
      float p3 = EXP2(st[jt][3]);
      ps += (p0 + p1) + (p2 + p3);
      unsigned int lo = pack_bf2(p0, p1);
      unsigned int hi = pack_bf2(p2, p3);
      *(uint2*)(&pw[i16 * 72 + jt * 16 + quad * 4]) = make_uint2(lo, hi);
    }
    lp += ps;

    // O^T += V · P^T  (same-wave LDS round-trip; dbuf kills the WAR)
    bf16x8 pf0 = *(const bf16x8*)(&pw[i16 * 72 + quad * 8]);
    bf16x8 pf1 = *(const bf16x8*)(&pw[i16 * 72 + 32 + quad * 8]);
    #pragma unroll
    for (int ct = 0; ct < 4; ct++) {
      acc[ct] = __builtin_amdgcn_mfma_f32_16x16x32_bf16(vf[2 * ct],     pf0, acc[ct], 0, 0, 0);
      acc[ct] = __builtin_amdgcn_mfma_f32_16x16x32_bf16(vf[2 * ct + 1], pf1, acc[ct], 0, 0, 0);
    }
    #pragma unroll
    for (int jt = 0; jt < 4; jt++) kfc[jt] = kfn[jt];
  }

  lp += __shfl_xor(lp, 16);
  lp += __shfl_xor(lp, 32);

  __syncthreads();                 // all P-tile reads done -> overlay obuf
  float* obuf = (float*)p_lds;     // [4][64][17] = 17408 B <= 18432 B
  #pragma unroll
  for (int ct = 0; ct < 4; ct++)
    #pragma unroll
    for (int r = 0; r < 4; r++)
      obuf[(w * 64 + ct * 16 + quad * 4 + r) * 17 + i16] = acc[ct][r];
  if (quad == 0) l_s[w][i16] = lp;
  __syncthreads();

  float* ob = opart + (size_t)bid * 1024;
  #pragma unroll
  for (int e0 = 0; e0 < 4; e0++) {
    int e = tid + e0 * 256, c = e >> 4, i = e & 15;
    ob[e] = obuf[c * 17 + i] + obuf[(64 + c) * 17 + i]
          + obuf[(128 + c) * 17 + i] + obuf[(192 + c) * 17 + i];
  }
  if (tid < 16)
    lpart[(size_t)bid * 16 + tid] =
        l_s[0][tid] + l_s[1][tid] + l_s[2][tid] + l_s[3][tid];
}

// ---------------------------------------------------------------------------
// Kernel 3: merge the 2 j-half partials + epilogue: y = gs*O/L + x
// ---------------------------------------------------------------------------
__global__ __launch_bounds__(256) void reduce_ep(
    const float* __restrict__ x,
    const float* __restrict__ opart, const float* __restrict__ lpart,
    const float* __restrict__ gamma_p, const float* __restrict__ dyn_p,
    float* __restrict__ y)
{
  const int bid = blockIdx.x;            // b*576 + rt
  const int b = bid / 576, rt = bid % 576;
  const int tid = threadIdx.x;
  const float gs = gamma_p[0] * dyn_p[0];
  const float* o0 = opart + (size_t)(bid * 2) * 1024;
  const float* o1 = o0 + 1024;
  const float* l0 = lpart + (size_t)(bid * 2) * 16;
  const float* l1 = l0 + 16;
  #pragma unroll
  for (int e0 = 0; e0 < 4; e0++) {
    int e = tid + e0 * 256, c = e >> 4, i = e & 15;
    float L = l0[i] + l1[i];
    float O = o0[e] + o1[e];
    size_t a = (size_t)(b * 64 + c) * NTOK + rt * 16 + i;
    y[a] = gs * O / L + x[a];
  }
}

// ---------------------------------------------------------------------------
extern "C" void kernel_launch(void* const* d_in, const int* in_sizes, int n_in,
                              void* d_out, int out_size, void* d_ws, size_t ws_size,
                              hipStream_t stream) {
  const float* x     = (const float*)d_in[0];
  const float* Wq    = (const float*)d_in[1];
  const float* bq    = (const float*)d_in[2];
  const float* Wk    = (const float*)d_in[3];
  const float* bk    = (const float*)d_in[4];
  const float* Wv    = (const float*)d_in[5];
  const float* bv    = (const float*)d_in[6];
  const float* gamma = (const float*)d_in[7];
  const float* dyn   = (const float*)d_in[8];
  float* y = (float*)d_out;

  // workspace layout (bf16 then f32, 16B-aligned boundaries)
  unsigned short* qg = (unsigned short*)d_ws;              // B*N*8
  unsigned short* kg = qg + (size_t)NBAT * NTOK * 8;       // B*N*8
  unsigned short* vg = kg + (size_t)NBAT * NTOK * 8;       // B*64*N
  float* opart = (float*)(vg + (size_t)NBAT * 64 * NTOK);  // 2304*1024
  float* lpart = opart + (size_t)2304 * 1024;              // 2304*16

  qkv_proj<<<NBAT * 144 * 5, 256, 0, stream>>>(x, Wq, bq, Wk, bk, Wv, bv, qg, kg, vg);
  flash_partial<<<NBAT * 576 * 2, 256, 0, stream>>>(qg, kg, vg, opart, lpart);
  reduce_ep<<<NBAT * 576, 256, 0, stream>>>(x, opart, lpart, gamma, dyn, y);
}

// Round 5
// 248.030 us; speedup vs baseline: 1.3063x; 1.0004x over previous
//
#include <hip/hip_runtime.h>

// Problem constants (B=2, C=64, C8=8, H=W=96 -> N=9216)
#define NTOK  9216
#define NBAT  2

typedef __attribute__((ext_vector_type(8))) short bf16x8;
typedef __attribute__((ext_vector_type(4))) float f32x4;

#if __has_builtin(__builtin_amdgcn_exp2f)
#define EXP2(x) __builtin_amdgcn_exp2f(x)
#else
#define EXP2(x) exp2f(x)
#endif
#define L2E 1.4426950408889634f

__device__ __forceinline__ unsigned short f2bf(float x) {
  unsigned int u = __builtin_bit_cast(unsigned int, x);
  u += 0x7fffu + ((u >> 16) & 1u);   // RNE
  return (unsigned short)(u >> 16);
}

// pack two non-negative floats to bf16x2 (round-half-up via +0x8000, v_perm)
__device__ __forceinline__ unsigned int pack_bf2(float lo, float hi) {
  unsigned int ulo = __builtin_bit_cast(unsigned int, lo) + 0x8000u;
  unsigned int uhi = __builtin_bit_cast(unsigned int, hi) + 0x8000u;
  return __builtin_amdgcn_perm(uhi, ulo, 0x07060302u);
}

// ---------------------------------------------------------------------------
// Kernel 1: QKV projections -> bf16.
//   qg[b][n][8]  = (q + bq) * log2(e)   (softmax exp folded into Q scale)
//   kg[b][n][8], vg[b][c][n]
// ---------------------------------------------------------------------------
__global__ __launch_bounds__(256) void qkv_proj(
    const float* __restrict__ x,
    const float* __restrict__ Wq, const float* __restrict__ bq,
    const float* __restrict__ Wk, const float* __restrict__ bk,
    const float* __restrict__ Wv, const float* __restrict__ bv,
    unsigned short* __restrict__ qg, unsigned short* __restrict__ kg,
    unsigned short* __restrict__ vg)
{
  __shared__ __align__(16) float xl[64 * 68];
  const int bid = blockIdx.x;
  const int rg  = bid % 5;
  const int t2  = bid / 5;
  const int nt  = t2 % 144;
  const int b   = t2 / 144;
  const int t   = threadIdx.x;
  const int lane = t & 63;
  const int n0  = nt * 64;

  #pragma unroll
  for (int kk = 0; kk < 4; kk++) {
    int p = t + kk * 256;
    int c = p >> 4, n4 = (p & 15) << 2;
    *(float4*)(&xl[c * 68 + n4]) =
        *(const float4*)(x + (size_t)(b * 64 + c) * NTOK + n0 + n4);
  }
  __syncthreads();

  const int g  = __builtin_amdgcn_readfirstlane(t >> 6);  // wave id 0..3
  const int r0 = rg * 16 + g * 4;                         // rows r0..r0+3 (0..79)

  const float* wbase; const float* bias_p; int lr0;
  if (r0 < 8)       { wbase = Wq; bias_p = bq; lr0 = r0; }
  else if (r0 < 16) { wbase = Wk; bias_p = bk; lr0 = r0 - 8; }
  else              { wbase = Wv; bias_p = bv; lr0 = r0 - 16; }
  const float* w0 = wbase + lr0 * 64;

  float a0 = 0.f, a1 = 0.f, a2 = 0.f, a3 = 0.f;
  #pragma unroll 16
  for (int c = 0; c < 64; c++) {
    float xv = xl[c * 68 + lane];
    a0 = fmaf(w0[c],       xv, a0);
    a1 = fmaf(w0[64 + c],  xv, a1);
    a2 = fmaf(w0[128 + c], xv, a2);
    a3 = fmaf(w0[192 + c], xv, a3);
  }
  a0 += bias_p[lr0]; a1 += bias_p[lr0 + 1];
  a2 += bias_p[lr0 + 2]; a3 += bias_p[lr0 + 3];
  if (r0 < 8) { a0 *= L2E; a1 *= L2E; a2 *= L2E; a3 *= L2E; }  // wave-uniform

  const int n = n0 + lane;
  if (r0 < 16) {
    ushort4 o;
    o.x = f2bf(a0); o.y = f2bf(a1); o.z = f2bf(a2); o.w = f2bf(a3);
    unsigned short* dst = (r0 < 8) ? qg : kg;
    *(ushort4*)(dst + ((size_t)b * NTOK + n) * 8 + lr0) = o;
  } else {
    vg[(size_t)(b * 64 + lr0)     * NTOK + n] = f2bf(a0);
    vg[(size_t)(b * 64 + lr0 + 1) * NTOK + n] = f2bf(a1);
    vg[(size_t)(b * 64 + lr0 + 2) * NTOK + n] = f2bf(a2);
    vg[(size_t)(b * 64 + lr0 + 3) * NTOK + n] = f2bf(a3);
  }
}

// ---------------------------------------------------------------------------
// Kernel 2: flash partial, software-pipelined P round-trip.
// Iteration it: [read P(it-1) + load V(it-1)] || [S(it) -> exp -> write P(it)]
// then PV(it-1). No chain shorter than one full iteration; loop-carried deps
// are accumulate-only. No barriers, no cross-lane ops in the loop.
// ---------------------------------------------------------------------------

// Stage A: S^T(it) mfma, K(next) prefetch, exp2/pack, ds_write -> buf[it&1]
#define STAGE_A(IT_, JNEXT_)                                                 \
  {                                                                          \
    f32x4 st[4];                                                             \
    _Pragma("unroll")                                                        \
    for (int jt = 0; jt < 4; jt++)                                           \
      st[jt] = __builtin_amdgcn_mfma_f32_16x16x32_bf16(kfc[jt], qf, z4, 0, 0, 0); \
    _Pragma("unroll")                                                        \
    for (int jt = 0; jt < 4; jt++)                                           \
      kfn[jt] = *(const bf16x8*)(kb + ((JNEXT_) + jt * 16) * 8 + koff);      \
    unsigned short* pwb = pb + ((IT_) & 1) * 1152;                           \
    float ps = 0.f;                                                          \
    _Pragma("unroll")                                                        \
    for (int jt = 0; jt < 4; jt++) {                                         \
      float p0 = EXP2(st[jt][0]);                                            \
      float p1 = EXP2(st[jt][1]);                                            \
      float p2 = EXP2(st[jt][2]);                                            \
      float p3 = EXP2(st[jt][3]);                                            \
      ps += (p0 + p1) + (p2 + p3);                                           \
      *(uint2*)(&pwb[i16 * 72 + jt * 16 + quad * 4]) =                       \
          make_uint2(pack_bf2(p0, p1), pack_bf2(p2, p3));                    \
    }                                                                        \
    lp += ps;                                                                \
    _Pragma("unroll")                                                        \
    for (int jt = 0; jt < 4; jt++) kfc[jt] = kfn[jt];                        \
  }

__global__ __launch_bounds__(256, 4) void flash_partial(
    const unsigned short* __restrict__ qg,
    const unsigned short* __restrict__ kg,
    const unsigned short* __restrict__ vg,
    float* __restrict__ opart, float* __restrict__ lpart)
{
  __shared__ __align__(16) unsigned short p_lds[4 * 2 * 16 * 72]; // dbuf/wave
  __shared__ float l_s[4][16];

  const int bid  = blockIdx.x;
  const int jh   = bid & 1;
  const int rt   = (bid >> 1) % 576;
  const int b    = (bid >> 1) / 576;
  const int tid  = threadIdx.x;
  const int w    = tid >> 6;
  const int lane = tid & 63;
  const int i16  = lane & 15;
  const int quad = lane >> 4;
  const int jbase = jh * 4608 + (w << 6);

  unsigned short* pb = &p_lds[w * 2304];

  // uniform bases (SGPR) + 32-bit lane offsets (VGPR) -> saddr-form loads
  const unsigned short* __restrict__ vb = vg + (size_t)b * 64 * NTOK;
  const unsigned short* __restrict__ kb = kg + (size_t)b * NTOK * 8;
  const int koff = i16 * 8;
  const int voff = i16 * NTOK + quad * 8;

  bf16x8 qf = {};
  if (quad == 0)
    qf = *(const bf16x8*)(qg + ((size_t)b * NTOK + rt * 16 + i16) * 8);

  f32x4 acc[4];
  #pragma unroll
  for (int ct = 0; ct < 4; ct++) acc[ct] = (f32x4){0.f, 0.f, 0.f, 0.f};
  float lp = 0.f;
  const f32x4 z4 = {0.f, 0.f, 0.f, 0.f};

  bf16x8 kfc[4], kfn[4];
  #pragma unroll
  for (int jt = 0; jt < 4; jt++)
    kfc[jt] = *(const bf16x8*)(kb + (jbase + jt * 16) * 8 + koff);

  // prologue: S(0)/exp(0)/write(0)
  STAGE_A(0, jbase + 256);

  for (int it = 1; it < 18; ++it) {
    const int jp = jbase + ((it - 1) << 8);     // PV target chunk
    // (1) early issue: P(it-1) read (landed last iter) + V(it-1) frags
    unsigned short* pr = pb + ((it - 1) & 1) * 1152;
    bf16x8 pf0 = *(const bf16x8*)(&pr[i16 * 72 + quad * 8]);
    bf16x8 pf1 = *(const bf16x8*)(&pr[i16 * 72 + 32 + quad * 8]);
    bf16x8 vf[8];
    #pragma unroll
    for (int ct = 0; ct < 4; ct++) {
      vf[2 * ct]     = *(const bf16x8*)(vb + ct * 16 * NTOK + voff + jp);
      vf[2 * ct + 1] = *(const bf16x8*)(vb + ct * 16 * NTOK + voff + jp + 32);
    }
    // (2) S(it) + exp + write P(it) into the other buffer
    const int jn = (it == 17) ? jbase : jbase + ((it + 1) << 8);
    STAGE_A(it, jn);
    // (3) PV(it-1)
    #pragma unroll
    for (int ct = 0; ct < 4; ct++) {
      acc[ct] = __builtin_amdgcn_mfma_f32_16x16x32_bf16(vf[2 * ct],     pf0, acc[ct], 0, 0, 0);
      acc[ct] = __builtin_amdgcn_mfma_f32_16x16x32_bf16(vf[2 * ct + 1], pf1, acc[ct], 0, 0, 0);
    }
  }

  // epilogue: PV(17)
  {
    const int jp = jbase + (17 << 8);
    unsigned short* pr = pb + (17 & 1) * 1152;
    bf16x8 pf0 = *(const bf16x8*)(&pr[i16 * 72 + quad * 8]);
    bf16x8 pf1 = *(const bf16x8*)(&pr[i16 * 72 + 32 + quad * 8]);
    #pragma unroll
    for (int ct = 0; ct < 4; ct++) {
      bf16x8 vf0 = *(const bf16x8*)(vb + ct * 16 * NTOK + voff + jp);
      bf16x8 vf1 = *(const bf16x8*)(vb + ct * 16 * NTOK + voff + jp + 32);
      acc[ct] = __builtin_amdgcn_mfma_f32_16x16x32_bf16(vf0, pf0, acc[ct], 0, 0, 0);
      acc[ct] = __builtin_amdgcn_mfma_f32_16x16x32_bf16(vf1, pf1, acc[ct], 0, 0, 0);
    }
  }

  lp += __shfl_xor(lp, 16);
  lp += __shfl_xor(lp, 32);

  __syncthreads();                 // all P-tile reads done -> overlay obuf
  float* obuf = (float*)p_lds;     // [4][64][17] = 17408 B <= 18432 B
  #pragma unroll
  for (int ct = 0; ct < 4; ct++)
    #pragma unroll
    for (int r = 0; r < 4; r++)
      obuf[(w * 64 + ct * 16 + quad * 4 + r) * 17 + i16] = acc[ct][r];
  if (quad == 0) l_s[w][i16] = lp;
  __syncthreads();

  float* ob = opart + (size_t)bid * 1024;
  #pragma unroll
  for (int e0 = 0; e0 < 4; e0++) {
    int e = tid + e0 * 256, c = e >> 4, i = e & 15;
    ob[e] = obuf[c * 17 + i] + obuf[(64 + c) * 17 + i]
          + obuf[(128 + c) * 17 + i] + obuf[(192 + c) * 17 + i];
  }
  if (tid < 16)
    lpart[(size_t)bid * 16 + tid] =
        l_s[0][tid] + l_s[1][tid] + l_s[2][tid] + l_s[3][tid];
}

// ---------------------------------------------------------------------------
// Kernel 3: merge the 2 j-half partials + epilogue: y = gs*O/L + x
// ---------------------------------------------------------------------------
__global__ __launch_bounds__(256) void reduce_ep(
    const float* __restrict__ x,
    const float* __restrict__ opart, const float* __restrict__ lpart,
    const float* __restrict__ gamma_p, const float* __restrict__ dyn_p,
    float* __restrict__ y)
{
  const int bid = blockIdx.x;            // b*576 + rt
  const int b = bid / 576, rt = bid % 576;
  const int tid = threadIdx.x;
  const float gs = gamma_p[0] * dyn_p[0];
  const float* o0 = opart + (size_t)(bid * 2) * 1024;
  const float* o1 = o0 + 1024;
  const float* l0 = lpart + (size_t)(bid * 2) * 16;
  const float* l1 = l0 + 16;
  #pragma unroll
  for (int e0 = 0; e0 < 4; e0++) {
    int e = tid + e0 * 256, c = e >> 4, i = e & 15;
    float L = l0[i] + l1[i];
    float O = o0[e] + o1[e];
    size_t a = (size_t)(b * 64 + c) * NTOK + rt * 16 + i;
    y[a] = gs * O / L + x[a];
  }
}

// ---------------------------------------------------------------------------
extern "C" void kernel_launch(void* const* d_in, const int* in_sizes, int n_in,
                              void* d_out, int out_size, void* d_ws, size_t ws_size,
                              hipStream_t stream) {
  const float* x     = (const float*)d_in[0];
  const float* Wq    = (const float*)d_in[1];
  const float* bq    = (const float*)d_in[2];
  const float* Wk    = (const float*)d_in[3];
  const float* bk    = (const float*)d_in[4];
  const float* Wv    = (const float*)d_in[5];
  const float* bv    = (const float*)d_in[6];
  const float* gamma = (const float*)d_in[7];
  const float* dyn   = (const float*)d_in[8];
  float* y = (float*)d_out;

  // workspace layout (bf16 then f32, 16B-aligned boundaries)
  unsigned short* qg = (unsigned short*)d_ws;              // B*N*8
  unsigned short* kg = qg + (size_t)NBAT * NTOK * 8;       // B*N*8
  unsigned short* vg = kg + (size_t)NBAT * NTOK * 8;       // B*64*N
  float* opart = (float*)(vg + (size_t)NBAT * 64 * NTOK);  // 2304*1024
  float* lpart = opart + (size_t)2304 * 1024;              // 2304*16

  qkv_proj<<<NBAT * 144 * 5, 256, 0, stream>>>(x, Wq, bq, Wk, bk, Wv, bv, qg, kg, vg);
  flash_partial<<<NBAT * 576 * 2, 256, 0, stream>>>(qg, kg, vg, opart, lpart);
  reduce_ep<<<NBAT * 576, 256, 0, stream>>>(x, opart, lpart, gamma, dyn, y);
}

// Round 6
// 178.621 us; speedup vs baseline: 1.8139x; 1.3886x over previous
//
#include <hip/hip_runtime.h>

// Problem constants (B=2, C=64, C8=8, H=W=96 -> N=9216)
#define NTOK  9216
#define NBAT  2

typedef __attribute__((ext_vector_type(8))) short bf16x8;
typedef __attribute__((ext_vector_type(4))) float f32x4;

#if __has_builtin(__builtin_amdgcn_exp2f)
#define EXP2(x) __builtin_amdgcn_exp2f(x)
#else
#define EXP2(x) exp2f(x)
#endif
#define L2E 1.4426950408889634f

__device__ __forceinline__ unsigned short f2bf(float x) {
  unsigned int u = __builtin_bit_cast(unsigned int, x);
  u += 0x7fffu + ((u >> 16) & 1u);   // RNE
  return (unsigned short)(u >> 16);
}

// pack two non-negative floats to bf16x2 (round-half-up via +0x8000, v_perm)
__device__ __forceinline__ unsigned int pack_bf2(float lo, float hi) {
  unsigned int ulo = __builtin_bit_cast(unsigned int, lo) + 0x8000u;
  unsigned int uhi = __builtin_bit_cast(unsigned int, hi) + 0x8000u;
  return __builtin_amdgcn_perm(uhi, ulo, 0x07060302u);
}

// ---------------------------------------------------------------------------
// Kernel 1: QKV projections -> bf16.
//   qg[b][n][8]  = (q + bq) * log2(e)   (softmax exp folded into Q scale)
//   kg[b][n][8], vg[b][c][n]
// ---------------------------------------------------------------------------
__global__ __launch_bounds__(256) void qkv_proj(
    const float* __restrict__ x,
    const float* __restrict__ Wq, const float* __restrict__ bq,
    const float* __restrict__ Wk, const float* __restrict__ bk,
    const float* __restrict__ Wv, const float* __restrict__ bv,
    unsigned short* __restrict__ qg, unsigned short* __restrict__ kg,
    unsigned short* __restrict__ vg)
{
  __shared__ __align__(16) float xl[64 * 68];
  const int bid = blockIdx.x;
  const int rg  = bid % 5;
  const int t2  = bid / 5;
  const int nt  = t2 % 144;
  const int b   = t2 / 144;
  const int t   = threadIdx.x;
  const int lane = t & 63;
  const int n0  = nt * 64;

  #pragma unroll
  for (int kk = 0; kk < 4; kk++) {
    int p = t + kk * 256;
    int c = p >> 4, n4 = (p & 15) << 2;
    *(float4*)(&xl[c * 68 + n4]) =
        *(const float4*)(x + (size_t)(b * 64 + c) * NTOK + n0 + n4);
  }
  __syncthreads();

  const int g  = __builtin_amdgcn_readfirstlane(t >> 6);  // wave id 0..3
  const int r0 = rg * 16 + g * 4;                         // rows r0..r0+3 (0..79)

  const float* wbase; const float* bias_p; int lr0;
  if (r0 < 8)       { wbase = Wq; bias_p = bq; lr0 = r0; }
  else if (r0 < 16) { wbase = Wk; bias_p = bk; lr0 = r0 - 8; }
  else              { wbase = Wv; bias_p = bv; lr0 = r0 - 16; }
  const float* w0 = wbase + lr0 * 64;

  float a0 = 0.f, a1 = 0.f, a2 = 0.f, a3 = 0.f;
  #pragma unroll 16
  for (int c = 0; c < 64; c++) {
    float xv = xl[c * 68 + lane];
    a0 = fmaf(w0[c],       xv, a0);
    a1 = fmaf(w0[64 + c],  xv, a1);
    a2 = fmaf(w0[128 + c], xv, a2);
    a3 = fmaf(w0[192 + c], xv, a3);
  }
  a0 += bias_p[lr0]; a1 += bias_p[lr0 + 1];
  a2 += bias_p[lr0 + 2]; a3 += bias_p[lr0 + 3];
  if (r0 < 8) { a0 *= L2E; a1 *= L2E; a2 *= L2E; a3 *= L2E; }  // wave-uniform

  const int n = n0 + lane;
  if (r0 < 16) {
    ushort4 o;
    o.x = f2bf(a0); o.y = f2bf(a1); o.z = f2bf(a2); o.w = f2bf(a3);
    unsigned short* dst = (r0 < 8) ? qg : kg;
    *(ushort4*)(dst + ((size_t)b * NTOK + n) * 8 + lr0) = o;
  } else {
    vg[(size_t)(b * 64 + lr0)     * NTOK + n] = f2bf(a0);
    vg[(size_t)(b * 64 + lr0 + 1) * NTOK + n] = f2bf(a1);
    vg[(size_t)(b * 64 + lr0 + 2) * NTOK + n] = f2bf(a2);
    vg[(size_t)(b * 64 + lr0 + 3) * NTOK + n] = f2bf(a3);
  }
}

// ---------------------------------------------------------------------------
// Kernel 2: flash partial. Each wave owns 32 query rows (2 subtiles) sharing
// one 64-j chunk per iteration -> V/K loads and P round-trip amortized 2x;
// total wave-iters halved vs r5. Unrolled x2 with alternating K frag banks
// (no copy -> no mid-body vmcnt(0) drain). P tile granule-XOR swizzled
// (<=2-way banks). Software-pipelined: PV(it-1) overlaps STAGE(it).
// ---------------------------------------------------------------------------

#define STAGE(IT_, KFU_, KFP_, JNEXT_)                                        \
  {                                                                           \
    unsigned short* pwb = pb + ((IT_) & 1) * 2304;                            \
    f32x4 st[4];                                                              \
    _Pragma("unroll")                                                         \
    for (int jt = 0; jt < 4; jt++)                                            \
      st[jt] = __builtin_amdgcn_mfma_f32_16x16x32_bf16(KFU_[jt], qf[0], z4, 0, 0, 0); \
    _Pragma("unroll")                                                         \
    for (int jt = 0; jt < 4; jt++)                                            \
      KFP_[jt] = *(const bf16x8*)(kb + ((JNEXT_) + jt * 16) * 8 + koff);      \
    {                                                                         \
      float ps = 0.f;                                                         \
      _Pragma("unroll")                                                       \
      for (int jt = 0; jt < 4; jt++) {                                        \
        float p0 = EXP2(st[jt][0]);                                           \
        float p1 = EXP2(st[jt][1]);                                           \
        float p2 = EXP2(st[jt][2]);                                           \
        float p3 = EXP2(st[jt][3]);                                           \
        ps += (p0 + p1) + (p2 + p3);                                          \
        *(uint2*)(&pwb[i16 * 72 + (((jt * 4 + quad) ^ sw) << 2)]) =           \
            make_uint2(pack_bf2(p0, p1), pack_bf2(p2, p3));                   \
      }                                                                       \
      lp0 += ps;                                                              \
    }                                                                         \
    _Pragma("unroll")                                                         \
    for (int jt = 0; jt < 4; jt++)                                            \
      st[jt] = __builtin_amdgcn_mfma_f32_16x16x32_bf16(KFU_[jt], qf[1], z4, 0, 0, 0); \
    {                                                                         \
      float ps = 0.f;                                                         \
      _Pragma("unroll")                                                       \
      for (int jt = 0; jt < 4; jt++) {                                        \
        float p0 = EXP2(st[jt][0]);                                           \
        float p1 = EXP2(st[jt][1]);                                           \
        float p2 = EXP2(st[jt][2]);                                           \
        float p3 = EXP2(st[jt][3]);                                           \
        ps += (p0 + p1) + (p2 + p3);                                          \
        *(uint2*)(&pwb[(16 + i16) * 72 + (((jt * 4 + quad) ^ sw) << 2)]) =    \
            make_uint2(pack_bf2(p0, p1), pack_bf2(p2, p3));                   \
      }                                                                       \
      lp1 += ps;                                                              \
    }                                                                         \
  }

#define BODY(IT_, KFU_, KFP_)                                                 \
  {                                                                           \
    const int jp = jbase + (((IT_) - 1) << 8);                                \
    const int jn = ((IT_) == 17) ? jbase : jbase + (((IT_) + 1) << 8);        \
    unsigned short* pr = pb + (((IT_) - 1) & 1) * 2304;                       \
    bf16x8 pf[2][2];                                                          \
    _Pragma("unroll")                                                         \
    for (int s = 0; s < 2; s++) {                                             \
      pf[s][0] = *(const bf16x8*)(&pr[(s * 16 + i16) * 72 + (((2 * quad) ^ sw) << 2)]); \
      pf[s][1] = *(const bf16x8*)(&pr[(s * 16 + i16) * 72 + (((8 + 2 * quad) ^ sw) << 2)]); \
    }                                                                         \
    bf16x8 vf0[4];                                                            \
    _Pragma("unroll")                                                         \
    for (int ct = 0; ct < 4; ct++)                                            \
      vf0[ct] = *(const bf16x8*)(vb + ct * 16 * NTOK + voff + jp);            \
    STAGE(IT_, KFU_, KFP_, jn);                                               \
    bf16x8 vf1[4];                                                            \
    _Pragma("unroll")                                                         \
    for (int ct = 0; ct < 4; ct++)                                            \
      vf1[ct] = *(const bf16x8*)(vb + ct * 16 * NTOK + voff + jp + 32);       \
    _Pragma("unroll")                                                         \
    for (int s = 0; s < 2; s++)                                               \
      _Pragma("unroll")                                                       \
      for (int ct = 0; ct < 4; ct++)                                          \
        acc[s][ct] = __builtin_amdgcn_mfma_f32_16x16x32_bf16(vf0[ct], pf[s][0], acc[s][ct], 0, 0, 0); \
    _Pragma("unroll")                                                         \
    for (int s = 0; s < 2; s++)                                               \
      _Pragma("unroll")                                                       \
      for (int ct = 0; ct < 4; ct++)                                          \
        acc[s][ct] = __builtin_amdgcn_mfma_f32_16x16x32_bf16(vf1[ct], pf[s][1], acc[s][ct], 0, 0, 0); \
  }

__global__ __launch_bounds__(256, 3) void flash_partial(
    const unsigned short* __restrict__ qg,
    const unsigned short* __restrict__ kg,
    const unsigned short* __restrict__ vg,
    float* __restrict__ opart, float* __restrict__ lpart)
{
  __shared__ __align__(16) unsigned short p_lds[4 * 2 * 32 * 72]; // 36864 B
  __shared__ float l_s[4][32];

  const int bid  = blockIdx.x;
  const int jh   = bid & 1;
  const int rt   = (bid >> 1) % 288;
  const int b    = (bid >> 1) / 288;
  const int tid  = threadIdx.x;
  const int w    = tid >> 6;
  const int lane = tid & 63;
  const int i16  = lane & 15;
  const int quad = lane >> 4;
  const int jbase = jh * 4608 + (w << 6);
  const int sw   = (i16 & 3) << 2;          // P-tile granule-XOR swizzle

  unsigned short* pb = &p_lds[w * 4608];

  const unsigned short* __restrict__ vb = vg + (size_t)b * 64 * NTOK;
  const unsigned short* __restrict__ kb = kg + (size_t)b * NTOK * 8;
  const int koff = i16 * 8;
  const int voff = i16 * NTOK + quad * 8;

  bf16x8 qf[2] = {};
  if (quad == 0) {
    qf[0] = *(const bf16x8*)(qg + ((size_t)b * NTOK + rt * 32 + i16) * 8);
    qf[1] = *(const bf16x8*)(qg + ((size_t)b * NTOK + rt * 32 + 16 + i16) * 8);
  }

  f32x4 acc[2][4];
  #pragma unroll
  for (int s = 0; s < 2; s++)
    #pragma unroll
    for (int ct = 0; ct < 4; ct++) acc[s][ct] = (f32x4){0.f, 0.f, 0.f, 0.f};
  float lp0 = 0.f, lp1 = 0.f;
  const f32x4 z4 = {0.f, 0.f, 0.f, 0.f};

  bf16x8 kfA[4], kfB[4];
  #pragma unroll
  for (int jt = 0; jt < 4; jt++)
    kfA[jt] = *(const bf16x8*)(kb + (jbase + jt * 16) * 8 + koff);

  STAGE(0, kfA, kfB, jbase + 256);
  for (int it2 = 0; it2 < 8; ++it2) {
    BODY(2 * it2 + 1, kfB, kfA);
    BODY(2 * it2 + 2, kfA, kfB);
  }
  BODY(17, kfB, kfA);

  // epilogue: PV(17)
  {
    const int jp = jbase + (17 << 8);
    unsigned short* pr = pb + 2304;   // buffer 17&1
    #pragma unroll
    for (int s = 0; s < 2; s++) {
      bf16x8 pf0 = *(const bf16x8*)(&pr[(s * 16 + i16) * 72 + (((2 * quad) ^ sw) << 2)]);
      bf16x8 pf1 = *(const bf16x8*)(&pr[(s * 16 + i16) * 72 + (((8 + 2 * quad) ^ sw) << 2)]);
      #pragma unroll
      for (int ct = 0; ct < 4; ct++) {
        bf16x8 vf0 = *(const bf16x8*)(vb + ct * 16 * NTOK + voff + jp);
        bf16x8 vf1 = *(const bf16x8*)(vb + ct * 16 * NTOK + voff + jp + 32);
        acc[s][ct] = __builtin_amdgcn_mfma_f32_16x16x32_bf16(vf0, pf0, acc[s][ct], 0, 0, 0);
        acc[s][ct] = __builtin_amdgcn_mfma_f32_16x16x32_bf16(vf1, pf1, acc[s][ct], 0, 0, 0);
      }
    }
  }

  lp0 += __shfl_xor(lp0, 16); lp0 += __shfl_xor(lp0, 32);
  lp1 += __shfl_xor(lp1, 16); lp1 += __shfl_xor(lp1, 32);
  if (quad == 0) { l_s[w][i16] = lp0; l_s[w][16 + i16] = lp1; }

  __syncthreads();                 // all P-tile reads done -> overlay obuf
  float* obuf = (float*)p_lds;     // [4][64][33] = 33792 B <= 36864 B
  #pragma unroll
  for (int s = 0; s < 2; s++)
    #pragma unroll
    for (int ct = 0; ct < 4; ct++)
      #pragma unroll
      for (int r = 0; r < 4; r++)
        obuf[w * 2112 + (ct * 16 + quad * 4 + r) * 33 + s * 16 + i16] = acc[s][ct][r];
  __syncthreads();

  float* ob = opart + (size_t)bid * 2048;
  #pragma unroll
  for (int e0 = 0; e0 < 8; e0++) {
    int e = tid + e0 * 256, c = e >> 5, r = e & 31;
    ob[e] = obuf[c * 33 + r] + obuf[2112 + c * 33 + r]
          + obuf[4224 + c * 33 + r] + obuf[6336 + c * 33 + r];
  }
  if (tid < 32)
    lpart[(size_t)bid * 32 + tid] =
        l_s[0][tid] + l_s[1][tid] + l_s[2][tid] + l_s[3][tid];
}

// ---------------------------------------------------------------------------
// Kernel 3: merge the 2 j-half partials + epilogue: y = gs*O/L + x
// ---------------------------------------------------------------------------
__global__ __launch_bounds__(256) void reduce_ep(
    const float* __restrict__ x,
    const float* __restrict__ opart, const float* __restrict__ lpart,
    const float* __restrict__ gamma_p, const float* __restrict__ dyn_p,
    float* __restrict__ y)
{
  const int bid = blockIdx.x;            // b*288 + rt
  const int b = bid / 288, rt = bid % 288;
  const int tid = threadIdx.x;
  const float gs = gamma_p[0] * dyn_p[0];
  const float* o0 = opart + (size_t)(bid * 2) * 2048;
  const float* o1 = o0 + 2048;
  const float* l0 = lpart + (size_t)(bid * 2) * 32;
  const float* l1 = l0 + 32;
  #pragma unroll
  for (int e0 = 0; e0 < 8; e0++) {
    int e = tid + e0 * 256, c = e >> 5, r = e & 31;
    float L = l0[r] + l1[r];
    float O = o0[e] + o1[e];
    size_t a = (size_t)(b * 64 + c) * NTOK + rt * 32 + r;
    y[a] = gs * O / L + x[a];
  }
}

// ---------------------------------------------------------------------------
extern "C" void kernel_launch(void* const* d_in, const int* in_sizes, int n_in,
                              void* d_out, int out_size, void* d_ws, size_t ws_size,
                              hipStream_t stream) {
  const float* x     = (const float*)d_in[0];
  const float* Wq    = (const float*)d_in[1];
  const float* bq    = (const float*)d_in[2];
  const float* Wk    = (const float*)d_in[3];
  const float* bk    = (const float*)d_in[4];
  const float* Wv    = (const float*)d_in[5];
  const float* bv    = (const float*)d_in[6];
  const float* gamma = (const float*)d_in[7];
  const float* dyn   = (const float*)d_in[8];
  float* y = (float*)d_out;

  // workspace layout (bf16 then f32, 16B-aligned boundaries)
  unsigned short* qg = (unsigned short*)d_ws;              // B*N*8
  unsigned short* kg = qg + (size_t)NBAT * NTOK * 8;       // B*N*8
  unsigned short* vg = kg + (size_t)NBAT * NTOK * 8;       // B*64*N
  float* opart = (float*)(vg + (size_t)NBAT * 64 * NTOK);  // 1152*2048
  float* lpart = opart + (size_t)1152 * 2048;              // 1152*32

  qkv_proj<<<NBAT * 144 * 5, 256, 0, stream>>>(x, Wq, bq, Wk, bk, Wv, bv, qg, kg, vg);
  flash_partial<<<NBAT * 288 * 2, 256, 0, stream>>>(qg, kg, vg, opart, lpart);
  reduce_ep<<<NBAT * 288, 256, 0, stream>>>(x, opart, lpart, gamma, dyn, y);
}